// Round 2
// 542.776 us; speedup vs baseline: 1.0571x; 1.0571x over previous
//
#include <hip/hip_runtime.h>

#define DF   512
#define HID2 512
#define NHID 256
#define NCLS 50
#define NB   512

typedef __attribute__((ext_vector_type(8))) short short8;
typedef __attribute__((ext_vector_type(4))) float float4v;

__device__ __forceinline__ float b2f(unsigned short u) {
    union { unsigned int i; float f; } v; v.i = ((unsigned int)u) << 16; return v.f;
}
__device__ __forceinline__ unsigned short f2b(float f) {
    union { float f; unsigned int u; } v; v.f = f;
    unsigned int r = v.u + 0x7FFFu + ((v.u >> 16) & 1u);
    return (unsigned short)(r >> 16);
}

// ---- preprocess mega-kernel: all independent prep work in ONE dispatch -----
// block roles (256 threads each):
//   [0,128)       : weight transpose fp32->bf16 (4 weights, 8x4 tiles of 64x64)
//   [128,384)     : gather h0 rows (512 rows, 2/block)
//   [384,2944)    : gather h1 rows (5120 rows, 2/block)
//   [2944,3200)   : h1mean = mean10(feat[s1]) fp32-accurate (512 groups, 2/block)
//   [3200,5760)   : h2mean = mean25(feat[s2]) (5120 groups, 2/block)
__global__ __launch_bounds__(256) void preprocess(
        const float* __restrict__ feat,
        const float* __restrict__ W0, const float* __restrict__ W1,
        const float* __restrict__ W2, const float* __restrict__ W3,
        unsigned short* __restrict__ Wt,
        const int* __restrict__ s0, const int* __restrict__ s1,
        const int* __restrict__ s2,
        unsigned short* __restrict__ h0bf, unsigned short* __restrict__ h1bf,
        unsigned short* __restrict__ h1mean, unsigned short* __restrict__ h2mean) {
    __shared__ unsigned short T[64][66];
    const int b = blockIdx.x;
    const int t = threadIdx.x;

    if (b < 128) {
        // weight transpose: W [512 k][256 n] fp32 -> Wt [256 n][512 k] bf16
        const int x = b & 7, y = (b >> 3) & 3, z = b >> 5;
        const float* W = (z == 0) ? W0 : (z == 1) ? W1 : (z == 2) ? W2 : W3;
        unsigned short* Out = Wt + (size_t)z * NHID * DF;
        const int k0 = x * 64, n0 = y * 64;
#pragma unroll
        for (int p = 0; p < 4; ++p) {
            const int k = p * 16 + (t >> 4);
            const int n = (t & 15) * 4;
            const float4 v = *(const float4*)(W + (size_t)(k0 + k) * NHID + n0 + n);
            T[n + 0][k] = f2b(v.x);
            T[n + 1][k] = f2b(v.y);
            T[n + 2][k] = f2b(v.z);
            T[n + 3][k] = f2b(v.w);
        }
        __syncthreads();
#pragma unroll
        for (int p = 0; p < 4; ++p) {
            const int n = p * 16 + (t >> 4);
            const int k = (t & 15) * 4;
            ushort4 o;
            o.x = T[n][k]; o.y = T[n][k + 1]; o.z = T[n][k + 2]; o.w = T[n][k + 3];
            *(ushort4*)(Out + (size_t)(n0 + n) * DF + k0 + k) = o;
        }
        return;
    }

    const int sub = t >> 7;          // 0/1: which row/group of this block
    const int col = (t & 127) * 4;   // float column offset (128 lanes x float4 = 2KB row)

    if (b < 384) {                   // gather h0
        const int r = (b - 128) * 2 + sub;
        const float4 v = *(const float4*)(feat + (size_t)s0[r] * DF + col);
        ushort4 o; o.x = f2b(v.x); o.y = f2b(v.y); o.z = f2b(v.z); o.w = f2b(v.w);
        *(ushort4*)(h0bf + (size_t)r * DF + col) = o;
        return;
    }
    if (b < 2944) {                  // gather h1
        const int r = (b - 384) * 2 + sub;
        const float4 v = *(const float4*)(feat + (size_t)s1[r] * DF + col);
        ushort4 o; o.x = f2b(v.x); o.y = f2b(v.y); o.z = f2b(v.z); o.w = f2b(v.w);
        *(ushort4*)(h1bf + (size_t)r * DF + col) = o;
        return;
    }
    if (b < 3200) {                  // h1mean (fp32-accurate mean of 10 feature rows)
        const int g = (b - 2944) * 2 + sub;
        float ax = 0.f, ay = 0.f, az = 0.f, aw = 0.f;
#pragma unroll
        for (int j = 0; j < 10; ++j) {
            const float4 v = *(const float4*)(feat + (size_t)s1[g * 10 + j] * DF + col);
            ax += v.x; ay += v.y; az += v.z; aw += v.w;
        }
        ushort4 o;
        o.x = f2b(ax * 0.1f); o.y = f2b(ay * 0.1f);
        o.z = f2b(az * 0.1f); o.w = f2b(aw * 0.1f);
        *(ushort4*)(h1mean + (size_t)g * DF + col) = o;
        return;
    }
    {                                // h2mean (mean of 25 feature rows)
        const int g = (b - 3200) * 2 + sub;
        float ax = 0.f, ay = 0.f, az = 0.f, aw = 0.f;
#pragma unroll
        for (int j = 0; j < 25; ++j) {
            const float4 v = *(const float4*)(feat + (size_t)s2[g * 25 + j] * DF + col);
            ax += v.x; ay += v.y; az += v.z; aw += v.w;
        }
        const float inv = 1.f / 25.f;
        ushort4 o;
        o.x = f2b(ax * inv); o.y = f2b(ay * inv);
        o.z = f2b(az * inv); o.w = f2b(aw * inv);
        *(ushort4*)(h2mean + (size_t)g * DF + col) = o;
    }
}

// ---- group mean of bf16 rows: 2 groups per 256-thread block ----------------
template <int GS>
__global__ void mean_bf16(const unsigned short* __restrict__ in,
                          unsigned short* __restrict__ out, float inv) {
    const int g = blockIdx.x * 2 + (threadIdx.x >> 7);
    const int col = (threadIdx.x & 127) * 4;
    float acc[4] = {0.f, 0.f, 0.f, 0.f};
#pragma unroll
    for (int j = 0; j < GS; ++j) {
        const ushort4 v = *(const ushort4*)(in + ((size_t)g * GS + j) * DF + col);
        acc[0] += b2f(v.x); acc[1] += b2f(v.y); acc[2] += b2f(v.z); acc[3] += b2f(v.w);
    }
    ushort4 o;
    o.x = f2b(acc[0] * inv); o.y = f2b(acc[1] * inv);
    o.z = f2b(acc[2] * inv); o.w = f2b(acc[3] * inv);
    *(ushort4*)(out + (size_t)g * DF + col) = o;
}

// ---- fused layer-0 GEMMs: n1 (M=5120, y<80) and n0 (M=512, y>=80) ----------
// C[M,512] = relu([A1@W1, A2@W2]); bf16 out. Tile 64m x 64n, BK=64, 4 waves.
__global__ __launch_bounds__(256) void gemm_fused01(
        const unsigned short* __restrict__ A1a, const unsigned short* __restrict__ A2a,
        const unsigned short* __restrict__ A1b, const unsigned short* __restrict__ A2b,
        const unsigned short* __restrict__ W1t, const unsigned short* __restrict__ W2t,
        unsigned short* __restrict__ C1, unsigned short* __restrict__ C2) {
    __shared__ unsigned short As[64][72];
    __shared__ unsigned short Bs[64][72];
    const int tid = threadIdx.x;
    const int wave = tid >> 6;
    const int lane = tid & 63;
    const bool second = (blockIdx.y >= 80);
    const int m0 = (second ? (blockIdx.y - 80) : blockIdx.y) * 64;
    const int nb = blockIdx.x * 64;
    const unsigned short* A1 = second ? A1b : A1a;
    const unsigned short* A2 = second ? A2b : A2a;
    unsigned short* C = second ? C2 : C1;
    const unsigned short* A  = (nb < 256) ? A1 : A2;
    const unsigned short* Wt = (nb < 256) ? W1t : W2t;
    const int n0 = nb & 255;

    const int sr = tid >> 3;
    const int sk = (tid & 7) * 8;

    float4v acc[4];
#pragma unroll
    for (int i = 0; i < 4; ++i) acc[i] = (float4v)(0.f);

    const int am = wave * 16 + (lane & 15);
    const int kq = (lane >> 4) * 8;

    for (int k0 = 0; k0 < DF; k0 += 64) {
        *(uint4*)&As[sr][sk]      = *(const uint4*)(A  + (size_t)(m0 + sr) * DF + k0 + sk);
        *(uint4*)&As[sr + 32][sk] = *(const uint4*)(A  + (size_t)(m0 + sr + 32) * DF + k0 + sk);
        *(uint4*)&Bs[sr][sk]      = *(const uint4*)(Wt + (size_t)(n0 + sr) * DF + k0 + sk);
        *(uint4*)&Bs[sr + 32][sk] = *(const uint4*)(Wt + (size_t)(n0 + sr + 32) * DF + k0 + sk);
        __syncthreads();
#pragma unroll
        for (int ks = 0; ks < 64; ks += 32) {
            const short8 af = *(const short8*)&As[am][ks + kq];
#pragma unroll
            for (int nt = 0; nt < 4; ++nt) {
                const short8 bf = *(const short8*)&Bs[nt * 16 + (lane & 15)][ks + kq];
                acc[nt] = __builtin_amdgcn_mfma_f32_16x16x32_bf16(af, bf, acc[nt], 0, 0, 0);
            }
        }
        __syncthreads();
    }

#pragma unroll
    for (int nt = 0; nt < 4; ++nt) {
        const int gcol = nb + nt * 16 + (lane & 15);
#pragma unroll
        for (int r = 0; r < 4; ++r) {
            const int grow = m0 + wave * 16 + (lane >> 4) * 4 + r;
            const float v = fmaxf(acc[nt][r], 0.f);
            C[(size_t)grow * HID2 + gcol] = f2b(v);
        }
    }
}

// ---- dual MFMA GEMM (generic): used for the final layer-1 GEMM -------------
__global__ __launch_bounds__(256) void gemm_dual_mfma(
        const unsigned short* __restrict__ A1, const unsigned short* __restrict__ A2,
        const unsigned short* __restrict__ W1t, const unsigned short* __restrict__ W2t,
        void* __restrict__ Cout, int relu, int cfp32) {
    __shared__ unsigned short As[64][72];
    __shared__ unsigned short Bs[64][72];
    const int tid = threadIdx.x;
    const int wave = tid >> 6;
    const int lane = tid & 63;
    const int m0 = blockIdx.y * 64;
    const int nb = blockIdx.x * 64;
    const unsigned short* A  = (nb < 256) ? A1 : A2;
    const unsigned short* Wt = (nb < 256) ? W1t : W2t;
    const int n0 = nb & 255;

    const int sr = tid >> 3;
    const int sk = (tid & 7) * 8;

    float4v acc[4];
#pragma unroll
    for (int i = 0; i < 4; ++i) acc[i] = (float4v)(0.f);

    const int am = wave * 16 + (lane & 15);
    const int kq = (lane >> 4) * 8;

    for (int k0 = 0; k0 < DF; k0 += 64) {
        *(uint4*)&As[sr][sk]      = *(const uint4*)(A  + (size_t)(m0 + sr) * DF + k0 + sk);
        *(uint4*)&As[sr + 32][sk] = *(const uint4*)(A  + (size_t)(m0 + sr + 32) * DF + k0 + sk);
        *(uint4*)&Bs[sr][sk]      = *(const uint4*)(Wt + (size_t)(n0 + sr) * DF + k0 + sk);
        *(uint4*)&Bs[sr + 32][sk] = *(const uint4*)(Wt + (size_t)(n0 + sr + 32) * DF + k0 + sk);
        __syncthreads();
#pragma unroll
        for (int ks = 0; ks < 64; ks += 32) {
            const short8 af = *(const short8*)&As[am][ks + kq];
#pragma unroll
            for (int nt = 0; nt < 4; ++nt) {
                const short8 bf = *(const short8*)&Bs[nt * 16 + (lane & 15)][ks + kq];
                acc[nt] = __builtin_amdgcn_mfma_f32_16x16x32_bf16(af, bf, acc[nt], 0, 0, 0);
            }
        }
        __syncthreads();
    }

#pragma unroll
    for (int nt = 0; nt < 4; ++nt) {
        const int gcol = nb + nt * 16 + (lane & 15);
#pragma unroll
        for (int r = 0; r < 4; ++r) {
            const int grow = m0 + wave * 16 + (lane >> 4) * 4 + r;
            float v = acc[nt][r];
            if (relu) v = fmaxf(v, 0.f);
            if (cfp32) ((float*)Cout)[(size_t)grow * HID2 + gcol] = v;
            else ((unsigned short*)Cout)[(size_t)grow * HID2 + gcol] = f2b(v);
        }
    }
}

// ---- normalize + prediction head: K split 4 ways across all waves ----------
__global__ __launch_bounds__(256) void normalize_pred(
        const float* __restrict__ outb,
        const float* __restrict__ Wp,
        const float* __restrict__ bp,
        float* __restrict__ logits) {
    __shared__ float row[HID2];
    __shared__ float red[256];
    __shared__ float part[4][64];
    const int r = blockIdx.x;
    const int t = threadIdx.x;
    const float2 v = *(const float2*)(outb + (size_t)r * HID2 + t * 2);
    row[t * 2] = v.x;
    row[t * 2 + 1] = v.y;
    red[t] = v.x * v.x + v.y * v.y;
    __syncthreads();
    for (int s = 128; s > 0; s >>= 1) {
        if (t < s) red[t] += red[t + s];
        __syncthreads();
    }
    const float scale = 1.0f / fmaxf(sqrtf(red[0]), 1e-12f);
    const int c = t & 63;        // output class (valid < 50)
    const int q = t >> 6;        // K-chunk (wave index)
    float acc = 0.f;
    if (c < NCLS) {
#pragma unroll 4
        for (int k = q * 128; k < q * 128 + 128; ++k) acc += row[k] * Wp[k * NCLS + c];
    }
    part[q][c] = acc;
    __syncthreads();
    if (t < NCLS) {
        logits[r * NCLS + t] =
            (part[0][t] + part[1][t] + part[2][t] + part[3][t]) * scale + bp[t];
    }
}

extern "C" void kernel_launch(void* const* d_in, const int* in_sizes, int n_in,
                              void* d_out, int out_size, void* d_ws, size_t ws_size,
                              hipStream_t stream) {
    const float* feat    = (const float*)d_in[0];
    const float* Wself0  = (const float*)d_in[1];
    const float* Wneigh0 = (const float*)d_in[2];
    const float* Wself1  = (const float*)d_in[3];
    const float* Wneigh1 = (const float*)d_in[4];
    const float* Wpred   = (const float*)d_in[5];
    const float* bpred   = (const float*)d_in[6];
    const int* s0 = (const int*)d_in[7];
    const int* s1 = (const int*)d_in[8];
    const int* s2 = (const int*)d_in[9];

    unsigned short* u = (unsigned short*)d_ws;
    unsigned short* h2mean = u;                         // 5120*512
    unsigned short* h1bf   = h2mean + 5120 * 512;       // 5120*512
    unsigned short* n1     = h1bf   + 5120 * 512;       // 5120*512
    unsigned short* h1mean = n1     + 5120 * 512;       // 512*512
    unsigned short* h0bf   = h1mean + 512 * 512;        // 512*512
    unsigned short* n1mean = h0bf   + 512 * 512;        // 512*512
    unsigned short* n0     = n1mean + 512 * 512;        // 512*512
    unsigned short* Wt     = n0     + 512 * 512;        // 4 * 256*512
    float* outb = (float*)(Wt + 4 * NHID * DF);         // 512*512 fp32
    unsigned short* Wt_s0 = Wt;
    unsigned short* Wt_n0 = Wt + 1 * NHID * DF;
    unsigned short* Wt_s1 = Wt + 2 * NHID * DF;
    unsigned short* Wt_n1 = Wt + 3 * NHID * DF;

    // L1: all independent preprocessing in one dispatch
    preprocess<<<5760, 256, 0, stream>>>(feat, Wself0, Wneigh0, Wself1, Wneigh1, Wt,
                                         s0, s1, s2, h0bf, h1bf, h1mean, h2mean);
    // L2: n1 (y 0..79) + n0 (y 80..87) fused — independent, share layer-0 weights
    gemm_fused01<<<dim3(8, 88), 256, 0, stream>>>(h1bf, h2mean, h0bf, h1mean,
                                                  Wt_s0, Wt_n0, n1, n0);
    // L3: n1mean
    mean_bf16<10><<<256, 256, 0, stream>>>(n1, n1mean, 0.1f);
    // L4: out = [n0@Ws1, n1mean@Wn1] fp32
    gemm_dual_mfma<<<dim3(8, 8), 256, 0, stream>>>(n0, n1mean, Wt_s1, Wt_n1, outb, 0, 1);
    // L5: L2-normalize + prediction head
    normalize_pred<<<NB, 256, 0, stream>>>(outb, Wpred, bpred, (float*)d_out);
}